// Round 1
// baseline (439.790 us; speedup 1.0000x reference)
//
#include <hip/hip_runtime.h>

#define H 20
#define NODE 480
#define BATCH 16384
#define BLK 256

// tanh(x) = 1 - 2/(e^{2x}+1); exp2-based, 2 transcendentals, saturates
// correctly for |x| -> inf without clamping (exp2->inf => rcp->0 => 1;
// exp2->0 => 1-2 = -1). abs err ~1e-6, threshold is 1.3e-2.
__device__ __forceinline__ float fast_tanh(float x) {
    float t = __builtin_amdgcn_exp2f(x * 2.8853900817779268f); // e^{2x}
    return 1.0f - 2.0f * __builtin_amdgcn_rcpf(t + 1.0f);
}

// One node g per block (weights wave-uniform -> s_load into SGPRs),
// one batch element per thread. No LDS: 800 ds_read/wave would bottleneck
// the per-CU LDS pipe; scalar K$ loads ride a separate pipe.
__global__ __launch_bounds__(BLK) void mlp480_kernel(
    const float* __restrict__ inputs,
    const float* __restrict__ W1, const float* __restrict__ b1,
    const float* __restrict__ W2, const float* __restrict__ b2,
    const float* __restrict__ W3, const float* __restrict__ b3,
    const float* __restrict__ W4, const float* __restrict__ b4,
    float* __restrict__ out)
{
    const int g = blockIdx.x;                 // node (fast dim: neighbors share input cache lines)
    const int b = blockIdx.y * BLK + threadIdx.x;

    // Wave-uniform weight bases (compiler: SGPR + s_load)
    const float* __restrict__ w1 = W1 + g * H;
    const float* __restrict__ bb1 = b1 + g * H;
    const float* __restrict__ w2 = W2 + g * H * H;
    const float* __restrict__ bb2 = b2 + g * H;
    const float* __restrict__ w3 = W3 + g * H * H;
    const float* __restrict__ bb3 = b3 + g * H;
    const float* __restrict__ w4 = W4 + g * H;
    const float bias4 = b4[g];

    const float x = inputs[b * NODE + g];

    float h[H], hn[H];

    // Layer 1: Linear(1,H) + tanh
#pragma unroll
    for (int j = 0; j < H; ++j)
        h[j] = fast_tanh(fmaf(x, w1[j], bb1[j]));

    // Layer 2: h W2 + b2, tanh   (einsum bgk,gkl->bgl: idx = k*H + l)
#pragma unroll
    for (int l = 0; l < H; ++l) {
        float acc = bb2[l];
#pragma unroll
        for (int k = 0; k < H; ++k)
            acc = fmaf(h[k], w2[k * H + l], acc);
        hn[l] = fast_tanh(acc);
    }

    // Layer 3
#pragma unroll
    for (int l = 0; l < H; ++l) {
        float acc = bb3[l];
#pragma unroll
        for (int k = 0; k < H; ++k)
            acc = fmaf(hn[k], w3[k * H + l], acc);
        h[l] = fast_tanh(acc);
    }

    // Layer 4: Linear(H,1)
    float acc = bias4;
#pragma unroll
    for (int k = 0; k < H; ++k)
        acc = fmaf(h[k], w4[k], acc);

    out[b * NODE + g] = acc;
}

extern "C" void kernel_launch(void* const* d_in, const int* in_sizes, int n_in,
                              void* d_out, int out_size, void* d_ws, size_t ws_size,
                              hipStream_t stream) {
    const float* inputs = (const float*)d_in[0];
    const float* W1 = (const float*)d_in[1];
    const float* b1 = (const float*)d_in[2];
    const float* W2 = (const float*)d_in[3];
    const float* b2 = (const float*)d_in[4];
    const float* W3 = (const float*)d_in[5];
    const float* b3 = (const float*)d_in[6];
    const float* W4 = (const float*)d_in[7];
    const float* b4 = (const float*)d_in[8];
    float* out = (float*)d_out;

    dim3 grid(NODE, BATCH / BLK);   // (480, 64)
    dim3 block(BLK);
    mlp480_kernel<<<grid, block, 0, stream>>>(inputs, W1, b1, W2, b2, W3, b3, W4, b4, out);
}

// Round 2
// 357.965 us; speedup vs baseline: 1.2286x; 1.2286x over previous
//
#include <hip/hip_runtime.h>

#define H 20
#define NODE 480
#define BATCH 16384
#define BLK 256

// tanh(x) = 1 - 2/(e^{2x}+1); 2 trans + 3 VALU, saturates correctly at +-inf.
__device__ __forceinline__ float fast_tanh(float x) {
    float t = __builtin_amdgcn_exp2f(x * 2.8853900817779268f); // e^{2x}
    return 1.0f - 2.0f * __builtin_amdgcn_rcpf(t + 1.0f);
}

// ---------------- transpose kernels (32x32 tile, LDS padded) ----------------
// A: src [BATCH][NODE] -> dst [NODE][BATCH]
__global__ __launch_bounds__(256) void transpose_in(const float* __restrict__ src,
                                                    float* __restrict__ dst) {
    __shared__ float t[32][33];
    const int gT = blockIdx.x * 32, bT = blockIdx.y * 32;
    const int tx = threadIdx.x, ty = threadIdx.y;
#pragma unroll
    for (int j = 0; j < 32; j += 8)
        t[ty + j][tx] = src[(bT + ty + j) * NODE + gT + tx];     // t[b_loc][g_loc]
    __syncthreads();
#pragma unroll
    for (int j = 0; j < 32; j += 8)
        dst[(gT + ty + j) * BATCH + bT + tx] = t[tx][ty + j];    // dst[g][b]=src[b][g]
}

// C: src [NODE][BATCH] -> dst [BATCH][NODE]
__global__ __launch_bounds__(256) void transpose_out(const float* __restrict__ src,
                                                     float* __restrict__ dst) {
    __shared__ float t[32][33];
    const int gT = blockIdx.x * 32, bT = blockIdx.y * 32;
    const int tx = threadIdx.x, ty = threadIdx.y;
#pragma unroll
    for (int j = 0; j < 32; j += 8)
        t[ty + j][tx] = src[(gT + ty + j) * BATCH + bT + tx];    // t[g_loc][b_loc]
    __syncthreads();
#pragma unroll
    for (int j = 0; j < 32; j += 8)
        dst[(bT + ty + j) * NODE + gT + tx] = t[tx][ty + j];     // dst[b][g]=src[g][b]
}

// ---------------- main kernel: one node g per block ----------------
// Loop-interchanged: k outer so each weight row w[k*H .. k*H+19] is a
// CONTIGUOUS wave-uniform read -> s_load_dwordx8/x16 batches instead of
// 400 scattered s_load_dword. acc[20] + h[20] stay in VGPRs (static idx).
template <bool TR>
__global__ __launch_bounds__(BLK) void mlp480_kernel(
    const float* __restrict__ inputs,
    const float* __restrict__ W1, const float* __restrict__ b1,
    const float* __restrict__ W2, const float* __restrict__ b2,
    const float* __restrict__ W3, const float* __restrict__ b3,
    const float* __restrict__ W4, const float* __restrict__ b4,
    float* __restrict__ out)
{
    const int g = blockIdx.x;
    const int b = blockIdx.y * BLK + threadIdx.x;

    const float* __restrict__ w1 = W1 + g * H;
    const float* __restrict__ bb1 = b1 + g * H;
    const float* __restrict__ w2 = W2 + g * H * H;
    const float* __restrict__ bb2 = b2 + g * H;
    const float* __restrict__ w3 = W3 + g * H * H;
    const float* __restrict__ bb3 = b3 + g * H;
    const float* __restrict__ w4 = W4 + g * H;
    const float bias4 = b4[g];

    const float x = TR ? inputs[g * BATCH + b] : inputs[b * NODE + g];

    float h[H], acc[H];

    // Layer 1
#pragma unroll
    for (int j = 0; j < H; ++j)
        h[j] = fast_tanh(fmaf(x, w1[j], bb1[j]));

    // Layer 2: k-outer, contiguous weight rows
#pragma unroll
    for (int l = 0; l < H; ++l) acc[l] = bb2[l];
#pragma unroll
    for (int k = 0; k < H; ++k) {
        const float hk = h[k];
        const float* __restrict__ row = w2 + k * H;
#pragma unroll
        for (int l = 0; l < H; ++l) acc[l] = fmaf(hk, row[l], acc[l]);
    }
#pragma unroll
    for (int l = 0; l < H; ++l) h[l] = fast_tanh(acc[l]);

    // Layer 3
#pragma unroll
    for (int l = 0; l < H; ++l) acc[l] = bb3[l];
#pragma unroll
    for (int k = 0; k < H; ++k) {
        const float hk = h[k];
        const float* __restrict__ row = w3 + k * H;
#pragma unroll
        for (int l = 0; l < H; ++l) acc[l] = fmaf(hk, row[l], acc[l]);
    }
#pragma unroll
    for (int l = 0; l < H; ++l) h[l] = fast_tanh(acc[l]);

    // Layer 4
    float o = bias4;
#pragma unroll
    for (int k = 0; k < H; ++k) o = fmaf(h[k], w4[k], o);

    if (TR) out[g * BATCH + b] = o;
    else    out[b * NODE + g] = o;
}

extern "C" void kernel_launch(void* const* d_in, const int* in_sizes, int n_in,
                              void* d_out, int out_size, void* d_ws, size_t ws_size,
                              hipStream_t stream) {
    const float* inputs = (const float*)d_in[0];
    const float* W1 = (const float*)d_in[1];
    const float* b1 = (const float*)d_in[2];
    const float* W2 = (const float*)d_in[3];
    const float* b2 = (const float*)d_in[4];
    const float* W3 = (const float*)d_in[5];
    const float* b3 = (const float*)d_in[6];
    const float* W4 = (const float*)d_in[7];
    const float* b4 = (const float*)d_in[8];
    float* out = (float*)d_out;

    const size_t planeBytes = (size_t)BATCH * NODE * sizeof(float); // 31.46 MB
    const dim3 mlpGrid(NODE, BATCH / BLK);

    if (ws_size >= 2 * planeBytes) {
        float* in_t  = (float*)d_ws;                    // [NODE][BATCH]
        float* out_t = (float*)((char*)d_ws + planeBytes);
        dim3 tGrid(NODE / 32, BATCH / 32), tBlk(32, 8);
        transpose_in<<<tGrid, tBlk, 0, stream>>>(inputs, in_t);
        mlp480_kernel<true><<<mlpGrid, BLK, 0, stream>>>(in_t, W1, b1, W2, b2,
                                                         W3, b3, W4, b4, out_t);
        transpose_out<<<tGrid, tBlk, 0, stream>>>(out_t, out);
    } else {
        mlp480_kernel<false><<<mlpGrid, BLK, 0, stream>>>(inputs, W1, b1, W2, b2,
                                                          W3, b3, W4, b4, out);
    }
}

// Round 4
// 288.733 us; speedup vs baseline: 1.5232x; 1.2398x over previous
//
#include <hip/hip_runtime.h>

#define H 20
#define NODE 480
#define BATCH 16384
#define BLK 256

typedef float v2f __attribute__((ext_vector_type(2)));

// tanh(x) = 1 - 2/(e^{2x}+1); 2 trans + 3 VALU, saturates correctly at +-inf.
__device__ __forceinline__ float fast_tanh(float x) {
    float t = __builtin_amdgcn_exp2f(x * 2.8853900817779268f); // e^{2x}
    return 1.0f - 2.0f * __builtin_amdgcn_rcpf(t + 1.0f);
}
__device__ __forceinline__ v2f tanh2(v2f v) {
    v2f r; r.x = fast_tanh(v.x); r.y = fast_tanh(v.y); return r;
}

// ---------------- transpose kernels (32x32 tile, LDS padded) ----------------
__global__ __launch_bounds__(256) void transpose_in(const float* __restrict__ src,
                                                    float* __restrict__ dst) {
    __shared__ float t[32][33];
    const int gT = blockIdx.x * 32, bT = blockIdx.y * 32;
    const int tx = threadIdx.x, ty = threadIdx.y;
#pragma unroll
    for (int j = 0; j < 32; j += 8)
        t[ty + j][tx] = src[(bT + ty + j) * NODE + gT + tx];
    __syncthreads();
#pragma unroll
    for (int j = 0; j < 32; j += 8)
        dst[(gT + ty + j) * BATCH + bT + tx] = t[tx][ty + j];
}

__global__ __launch_bounds__(256) void transpose_out(const float* __restrict__ src,
                                                     float* __restrict__ dst) {
    __shared__ float t[32][33];
    const int gT = blockIdx.x * 32, bT = blockIdx.y * 32;
    const int tx = threadIdx.x, ty = threadIdx.y;
#pragma unroll
    for (int j = 0; j < 32; j += 8)
        t[ty + j][tx] = src[(gT + ty + j) * BATCH + bT + tx];
    __syncthreads();
#pragma unroll
    for (int j = 0; j < 32; j += 8)
        dst[(bT + ty + j) * NODE + gT + tx] = t[tx][ty + j];
}

// ---------------- main kernel ----------------
// __launch_bounds__(BLK, 1): round-2 showed VGPR_Count=24 with 40+ live floats
// -> allocator was spilling h[]/acc[] to AGPRs (v_accvgpr moves = VALU slots).
// min-waves=1 unconstrains it. float2 packing -> v_pk_fma_f32: 2 FMA/slot.
template <bool TR>
__global__ __launch_bounds__(BLK, 1) void mlp480_kernel(
    const float* __restrict__ inputs,
    const float* __restrict__ W1, const float* __restrict__ b1,
    const float* __restrict__ W2, const float* __restrict__ b2,
    const float* __restrict__ W3, const float* __restrict__ b3,
    const float* __restrict__ W4, const float* __restrict__ b4,
    float* __restrict__ out)
{
    const int g = blockIdx.x;
    const int b = blockIdx.y * BLK + threadIdx.x;

    const v2f* __restrict__ w1v = (const v2f*)(W1 + g * H);
    const v2f* __restrict__ b1v = (const v2f*)(b1 + g * H);
    const v2f* __restrict__ b2v = (const v2f*)(b2 + g * H);
    const v2f* __restrict__ b3v = (const v2f*)(b3 + g * H);
    const v2f* __restrict__ w4v = (const v2f*)(W4 + g * H);
    const float* __restrict__ w2 = W2 + g * H * H;
    const float* __restrict__ w3 = W3 + g * H * H;
    const float bias4 = b4[g];

    const float x = TR ? inputs[g * BATCH + b] : inputs[b * NODE + g];
    const v2f x2 = {x, x};

    v2f h2[10], a2[10];

    // Layer 1: Linear(1,H) + tanh  (10 pk_fma)
#pragma unroll
    for (int j = 0; j < 10; ++j)
        h2[j] = tanh2(x2 * w1v[j] + b1v[j]);

    // Layer 2: k-outer, contiguous wave-uniform rows, 10 pk_fma per k
#pragma unroll
    for (int l = 0; l < 10; ++l) a2[l] = b2v[l];
#pragma unroll
    for (int k = 0; k < H; ++k) {
        const float hk = (k & 1) ? h2[k >> 1].y : h2[k >> 1].x;
        const v2f hk2 = {hk, hk};
        const v2f* __restrict__ row = (const v2f*)(w2 + k * H);
#pragma unroll
        for (int l = 0; l < 10; ++l) a2[l] = hk2 * row[l] + a2[l];
    }
#pragma unroll
    for (int l = 0; l < 10; ++l) h2[l] = tanh2(a2[l]);

    // Layer 3
#pragma unroll
    for (int l = 0; l < 10; ++l) a2[l] = b3v[l];
#pragma unroll
    for (int k = 0; k < H; ++k) {
        const float hk = (k & 1) ? h2[k >> 1].y : h2[k >> 1].x;
        const v2f hk2 = {hk, hk};
        const v2f* __restrict__ row = (const v2f*)(w3 + k * H);
#pragma unroll
        for (int l = 0; l < 10; ++l) a2[l] = hk2 * row[l] + a2[l];
    }
#pragma unroll
    for (int l = 0; l < 10; ++l) h2[l] = tanh2(a2[l]);

    // Layer 4: Linear(H,1)  (10 pk_fma + horizontal add)
    v2f s2 = {bias4, 0.0f};
#pragma unroll
    for (int k = 0; k < 10; ++k) s2 = h2[k] * w4v[k] + s2;
    const float o = s2.x + s2.y;

    if (TR) out[g * BATCH + b] = o;
    else    out[b * NODE + g] = o;
}

extern "C" void kernel_launch(void* const* d_in, const int* in_sizes, int n_in,
                              void* d_out, int out_size, void* d_ws, size_t ws_size,
                              hipStream_t stream) {
    const float* inputs = (const float*)d_in[0];
    const float* W1 = (const float*)d_in[1];
    const float* b1 = (const float*)d_in[2];
    const float* W2 = (const float*)d_in[3];
    const float* b2 = (const float*)d_in[4];
    const float* W3 = (const float*)d_in[5];
    const float* b3 = (const float*)d_in[6];
    const float* W4 = (const float*)d_in[7];
    const float* b4 = (const float*)d_in[8];
    float* out = (float*)d_out;

    const size_t planeBytes = (size_t)BATCH * NODE * sizeof(float);
    const dim3 mlpGrid(NODE, BATCH / BLK);

    if (ws_size >= 2 * planeBytes) {
        float* in_t  = (float*)d_ws;
        float* out_t = (float*)((char*)d_ws + planeBytes);
        dim3 tGrid(NODE / 32, BATCH / 32), tBlk(32, 8);
        transpose_in<<<tGrid, tBlk, 0, stream>>>(inputs, in_t);
        mlp480_kernel<true><<<mlpGrid, BLK, 0, stream>>>(in_t, W1, b1, W2, b2,
                                                         W3, b3, W4, b4, out_t);
        transpose_out<<<tGrid, tBlk, 0, stream>>>(out_t, out);
    } else {
        mlp480_kernel<false><<<mlpGrid, BLK, 0, stream>>>(inputs, W1, b1, W2, b2,
                                                          W3, b3, W4, b4, out);
    }
}